// Round 16
// baseline (314.373 us; speedup 1.0000x reference)
//
#include <hip/hip_runtime.h>

typedef __attribute__((ext_vector_type(8))) __bf16 bf16x8;
typedef __attribute__((ext_vector_type(4))) float f4;
typedef __attribute__((ext_vector_type(2))) unsigned int u32x2;

#define MFMA(a, b, c) __builtin_amdgcn_mfma_f32_16x16x32_bf16((a), (b), (c), 0, 0, 0)

// geometry: N=64 tokens, C=384, H=12 heads, HD=32, NW=36 masks, B=2304 windows
// ws layout (bytes):
//   [0, 196608)         bias_t  f32 [12][64][64]  (PRE-SCALED by log2e)
//   [196608, 1081344)   qkvp    bf16 B-fragments: frag=(nb*12+ks), nb in [0,72)
//   [1081344, 1376256)  projp   bf16 B-fragments: nb in [0,24)
//   [1376256, 1387056)  table   f32 [225][12]
//   [1387056, 1405488)  maskb   u64 [36][64] packed mask bits (1 = masked)

__device__ inline unsigned pk2(float a, float b) {
  unsigned short ha = __builtin_bit_cast(unsigned short, (__bf16)a);
  unsigned short hb = __builtin_bit_cast(unsigned short, (__bf16)b);
  return (unsigned)ha | ((unsigned)hb << 16);
}

// Fused prep: blocks [0,288) pack_w, [288,297) maskbits, [297,354) rpe_table (4 pts/block)
__global__ void k_prep(const float* __restrict__ qkv_w,
                       const float* __restrict__ proj_w,
                       const float* __restrict__ mask,
                       const float* __restrict__ coords,
                       const float* __restrict__ w1,
                       const float* __restrict__ b1,
                       const float* __restrict__ w2,
                       __bf16* __restrict__ qkvp, __bf16* __restrict__ projp,
                       unsigned long long* __restrict__ maskb,
                       float* __restrict__ table) {
  const int blk = blockIdx.x;
  if (blk < 288) {
    const int gid = blk * 256 + threadIdx.x;  // 73728 total
    const int frag = gid >> 6, lane = gid & 63;
    const int lr = lane & 15, lhi = lane >> 4;
    const float* src;
    __bf16* dst;
    if (frag < 864) {
      const int nb = frag / 12, ks = frag % 12;
      src = qkv_w + (nb * 16 + lr) * 384 + ks * 32 + lhi * 8;
      dst = qkvp + (size_t)frag * 512 + lane * 8;
    } else {
      const int f2 = frag - 864;
      const int nb = f2 / 12, ks = f2 % 12;
      src = proj_w + (nb * 16 + lr) * 384 + ks * 32 + lhi * 8;
      dst = projp + (size_t)f2 * 512 + lane * 8;
    }
#pragma unroll
    for (int j = 0; j < 8; ++j) dst[j] = (__bf16)src[j];
  } else if (blk < 297) {
    const int i = (blk - 288) * 256 + threadIdx.x;  // 2304 total
    const float* mrow = mask + (size_t)i * 64;
    unsigned long long bits = 0ull;
#pragma unroll
    for (int k = 0; k < 64; ++k)
      bits |= (unsigned long long)(mrow[k] < -50.f ? 1u : 0u) << k;
    maskb[i] = bits;
  } else {
    const int p = (blk - 297) * 4 + (threadIdx.x >> 6);  // 0..227, guard 225
    const int lane = threadIdx.x & 63;
    if (p >= 225) return;
    const float c0 = coords[p * 2 + 0], c1 = coords[p * 2 + 1];
    float hm[8];
#pragma unroll
    for (int t = 0; t < 8; ++t) {
      const int j = lane * 8 + t;
      float v = fmaf(c0, w1[j * 2 + 0], fmaf(c1, w1[j * 2 + 1], b1[j]));
      hm[t] = v > 0.f ? v : 0.f;
    }
    for (int h = 0; h < 12; ++h) {
      float s = 0.f;
#pragma unroll
      for (int t = 0; t < 8; ++t) s = fmaf(hm[t], w2[h * 512 + lane * 8 + t], s);
      for (int off = 32; off >= 1; off >>= 1) s += __shfl_xor(s, off);
      if (lane == 0) table[p * 12 + h] = s;
    }
  }
}

__global__ void k_bias_gather(const float* __restrict__ table,
                              const int* __restrict__ rel,
                              float* __restrict__ bias_t) {
  const int idx = blockIdx.x * 256 + threadIdx.x;  // 49152 total
  const int h = idx >> 12;
  const int r = idx & 4095;
  // pre-scale by log2(e): softmax runs in exp2 domain
  bias_t[idx] = table[rel[r] * 12 + h] * 1.4426950408889634f;
}

// Fused kernel: one window per block; 768 threads = 12 waves, ONE head per wave.
// LDS: [0,49152)  X bf16 64 rows * 768B, byte ^= ((row&7)<<4)
//      [49152 + w*9216): wave-private q (64*72B) / k (+4608, 64*72B);
//         P overlays both (64*144B); O then overlays q (64*72B) and is read
//         CROSS-WAVE by the proj phase (wave w reads buffer ks for K-step ks).
// Phases: stage X | MERGED qkv proj (one A-read -> 6 MFMAs, 96 accs, reg-budgeted)
//         | S^T=mfma(K,Q) (exp2-domain: q pre-scaled by scale*log2e)
//         | no-max softmax (bitmask, UNNORMALIZED P; inv kept) | PV (V via lane shuffle)
//         | O *= inv (deferred norm) | O->own buffer | ONE barrier | proj GEMM (cross-wave A)
__global__ __launch_bounds__(768, 3) void k_fused(
    const float* __restrict__ x, const unsigned long long* __restrict__ maskb,
    const float* __restrict__ q_bias, const float* __restrict__ v_bias,
    const float* __restrict__ bias_t, const bf16x8* __restrict__ qkvp,
    const bf16x8* __restrict__ projp, const float* __restrict__ proj_b,
    float* __restrict__ out) {
  __shared__ __align__(16) char lds[159744];
  const int tid = threadIdx.x;
  const int b = blockIdx.x;
  const int w = tid >> 6, lane = tid & 63;
  const int lr = lane & 15, lhi = lane >> 4;
  const int h = w;  // one head per wave
  char* wb = lds + 49152 + w * 9216;
  const int mb = b % 36;
  // scale * log2(e): S^T lands directly in the exp2 domain
  const float scale = 0.17677669529663687f * 1.4426950408889634f;
  const f4 fz = {0.f, 0.f, 0.f, 0.f};

  // hoist first qkv weight loads: latency hides under X staging
  const bf16x8* fq = qkvp + h * 1536 + lane;
  const bf16x8* fk = qkvp + 18432 + h * 1536 + lane;
  const bf16x8* fv = qkvp + 36864 + h * 1536 + lane;
  bf16x8 cq0 = fq[0], cq1 = fq[768];
  bf16x8 ck0 = fk[0], ck1 = fk[768];
  bf16x8 cv0 = fv[0], cv1 = fv[768];

  // ---- stage X (64x384 fp32 -> bf16) into swizzled LDS ----
  {
    const f4* xp = (const f4*)(x + (size_t)b * 24576);
#pragma unroll
    for (int it = 0; it < 8; ++it) {
      const int idx = tid + it * 768;  // 0..6143 float4's
      const int row = idx / 96;
      const int c4 = idx % 96;
      f4 v = xp[idx];
      unsigned long long pkw =
          (unsigned long long)pk2(v[0], v[1]) |
          ((unsigned long long)pk2(v[2], v[3]) << 32);
      *(unsigned long long*)(lds + row * 768 + ((c4 * 8) ^ ((row & 7) << 4))) = pkw;
    }
  }
  __syncthreads();

  // ---- MERGED q,k,v projection (64x32 each, K=384): mi-inner, 1 A-read -> 6 MFMAs ----
  unsigned pkv[4][2][2];
  {
    f4 aq[4][2], ak[4][2], av[4][2];
#pragma unroll
    for (int mi = 0; mi < 4; ++mi)
#pragma unroll
      for (int nj = 0; nj < 2; ++nj) {
        aq[mi][nj] = fz;
        ak[mi][nj] = fz;
        av[mi][nj] = fz;
      }
#pragma unroll
    for (int ks = 0; ks < 12; ++ks) {
#pragma unroll
      for (int mi = 0; mi < 4; ++mi) {
        const int row = mi * 16 + lr;
        const bf16x8 a = *(const bf16x8*)(lds + row * 768 +
                                          ((ks * 64 + lhi * 16) ^ ((row & 7) << 4)));
        __builtin_amdgcn_s_setprio(1);
        aq[mi][0] = MFMA(a, cq0, aq[mi][0]);
        aq[mi][1] = MFMA(a, cq1, aq[mi][1]);
        ak[mi][0] = MFMA(a, ck0, ak[mi][0]);
        ak[mi][1] = MFMA(a, ck1, ak[mi][1]);
        av[mi][0] = MFMA(a, cv0, av[mi][0]);
        av[mi][1] = MFMA(a, cv1, av[mi][1]);
        __builtin_amdgcn_s_setprio(0);
      }
      // prefetch-lite: next-ks weights into the same SSA vars (no dual reg set)
      const int kn = ks < 11 ? ks + 1 : 0;  // clamped: values unused at ks=11
      cq0 = fq[kn * 64];
      cq1 = fq[(12 + kn) * 64];
      ck0 = fk[kn * 64];
      ck1 = fk[(12 + kn) * 64];
      cv0 = fv[kn * 64];
      cv1 = fv[(12 + kn) * 64];
    }
    // scatter q (bias+scale·log2e), k into wave-private LDS; pack v into registers
    const float qb0 = q_bias[h * 32 + lr], qb1 = q_bias[h * 32 + 16 + lr];
    const float vb0 = v_bias[h * 32 + lr], vb1 = v_bias[h * 32 + 16 + lr];
#pragma unroll
    for (int mi = 0; mi < 4; ++mi) {
#pragma unroll
      for (int r = 0; r < 4; ++r) {
        const int row = mi * 16 + lhi * 4 + r;  // token
        *(__bf16*)(wb + row * 72 + lr * 2) = (__bf16)((aq[mi][0][r] + qb0) * scale);
        *(__bf16*)(wb + row * 72 + (16 + lr) * 2) = (__bf16)((aq[mi][1][r] + qb1) * scale);
        *(__bf16*)(wb + 4608 + row * 72 + lr * 2) = (__bf16)ak[mi][0][r];
        *(__bf16*)(wb + 4608 + row * 72 + (16 + lr) * 2) = (__bf16)ak[mi][1][r];
      }
      pkv[mi][0][0] = pk2(av[mi][0][0] + vb0, av[mi][0][1] + vb0);
      pkv[mi][0][1] = pk2(av[mi][0][2] + vb0, av[mi][0][3] + vb0);
      pkv[mi][1][0] = pk2(av[mi][1][0] + vb1, av[mi][1][1] + vb1);
      pkv[mi][1][1] = pk2(av[mi][1][2] + vb1, av[mi][1][3] + vb1);
    }
  }

  // ---- S^T = mfma(K, Q): st[mi][nj] holds S[q = nj*16+lr][k = mi*16+lhi*4+r] ----
  f4 st[4][4];
  {
    bf16x8 fqv[4], fkv[4];
#pragma unroll
    for (int i = 0; i < 4; ++i) {
      const int rt = i * 16 + lr;
      fqv[i] = *(const bf16x8*)(wb + rt * 72 + lhi * 16);          // Q frag
      fkv[i] = *(const bf16x8*)(wb + 4608 + rt * 72 + lhi * 16);   // K frag
    }
    __builtin_amdgcn_s_setprio(1);
#pragma unroll
    for (int mi = 0; mi < 4; ++mi)
#pragma unroll
      for (int nj = 0; nj < 4; ++nj) st[mi][nj] = MFMA(fkv[mi], fqv[nj], fz);
    __builtin_amdgcn_s_setprio(0);
  }

  // ---- no-max softmax (exp2 domain, bitmask); UNNORMALIZED P -> 144-stride LDS ----
  float inv0, inv1, inv2, inv3;
  {
    const float* bp = bias_t + h * 4096;
    const unsigned long long* mbp = maskb + mb * 64;
    float invs[4];
#pragma unroll
    for (int nj = 0; nj < 4; ++nj) {
      const int q = nj * 16 + lr;
      const unsigned long long mbits = mbp[q];
      float lsum = 0.f;
#pragma unroll
      for (int mi = 0; mi < 4; ++mi) {
        const int kbase = mi * 16 + lhi * 4;
        const f4 bb = *(const f4*)(bp + q * 64 + kbase);
        const unsigned b4 = (unsigned)(mbits >> kbase) & 0xFu;
        f4 e;
#pragma unroll
        for (int r = 0; r < 4; ++r)
          e[r] = ((b4 >> r) & 1u) ? 0.f : exp2f(st[mi][nj][r] + bb[r]);
        lsum += (e[0] + e[1]) + (e[2] + e[3]);
        u32x2 pw;
        pw[0] = pk2(e[0], e[1]);
        pw[1] = pk2(e[2], e[3]);
        *(u32x2*)(wb + q * 144 + mi * 32 + lhi * 8) = pw;
      }
      lsum += __shfl_xor(lsum, 16);
      lsum += __shfl_xor(lsum, 32);
      invs[nj] = 1.0f / lsum;
    }
    inv0 = invs[0]; inv1 = invs[1]; inv2 = invs[2]; inv3 = invs[3];
  }

  // ---- O = P V : P from 144-stride LDS (conflict-free b128), V via lane shuffle ----
  f4 o[4][2];
#pragma unroll
  for (int mi = 0; mi < 4; ++mi) {
    o[mi][0] = fz;
    o[mi][1] = fz;
  }
  {
    const int srcA = lr + 32 * (lhi & 1);
    const int srcB = srcA + 16;
    const bool hiSel = lhi >= 2;
#pragma unroll
    for (int kh = 0; kh < 2; ++kh) {
      bf16x8 pa[4];
#pragma unroll
      for (int mi = 0; mi < 4; ++mi) {
        const int row = mi * 16 + lr;
        pa[mi] = *(const bf16x8*)(wb + row * 144 + kh * 64 + lhi * 16);
      }
      bf16x8 vv[2];
#pragma unroll
      for (int nj = 0; nj < 2; ++nj) {
        const unsigned a0 = (unsigned)__shfl((int)pkv[2 * kh][nj][0], srcA);
        const unsigned b0 = (unsigned)__shfl((int)pkv[2 * kh + 1][nj][0], srcA);
        const unsigned a1 = (unsigned)__shfl((int)pkv[2 * kh][nj][1], srcA);
        const unsigned b1 = (unsigned)__shfl((int)pkv[2 * kh + 1][nj][1], srcA);
        const unsigned a2 = (unsigned)__shfl((int)pkv[2 * kh][nj][0], srcB);
        const unsigned b2 = (unsigned)__shfl((int)pkv[2 * kh + 1][nj][0], srcB);
        const unsigned a3 = (unsigned)__shfl((int)pkv[2 * kh][nj][1], srcB);
        const unsigned b3 = (unsigned)__shfl((int)pkv[2 * kh + 1][nj][1], srcB);
        union {
          unsigned u[4];
          bf16x8 v8;
        } cv;
        cv.u[0] = hiSel ? b0 : a0;
        cv.u[1] = hiSel ? b1 : a1;
        cv.u[2] = hiSel ? b2 : a2;
        cv.u[3] = hiSel ? b3 : a3;
        vv[nj] = cv.v8;
      }
      __builtin_amdgcn_s_setprio(1);
#pragma unroll
      for (int mi = 0; mi < 4; ++mi) {
        o[mi][0] = MFMA(pa[mi], vv[0], o[mi][0]);
        o[mi][1] = MFMA(pa[mi], vv[1], o[mi][1]);
      }
      __builtin_amdgcn_s_setprio(0);
    }
  }

  // ---- deferred normalization: o[mi][*][r] *= inv(token = mi*16 + lhi*4 + r) ----
#pragma unroll
  for (int mi = 0; mi < 4; ++mi) {
    const float ivn = (mi == 0) ? inv0 : (mi == 1) ? inv1 : (mi == 2) ? inv2 : inv3;
#pragma unroll
    for (int r = 0; r < 4; ++r) {
      const float iv = __shfl(ivn, lhi * 4 + r);
      o[mi][0][r] *= iv;
      o[mi][1][r] *= iv;
    }
  }

  // ---- hoist proj weight first-loads: L2 latency hides under scatter + barrier ----
  const bf16x8* fw = projp + w * 1536 + lane;
  bf16x8 cw0 = fw[0], cw1 = fw[768];

  // ---- O -> own buffer (72-stride, conflict-free; overlays dead q/P region) ----
#pragma unroll
  for (int mi = 0; mi < 4; ++mi) {
#pragma unroll
    for (int r = 0; r < 4; ++r) {
      const int row = mi * 16 + lhi * 4 + r;
      *(__bf16*)(wb + row * 72 + lr * 2) = (__bf16)o[mi][0][r];
      *(__bf16*)(wb + row * 72 + (16 + lr) * 2) = (__bf16)o[mi][1][r];
    }
  }
  __syncthreads();  // the ONLY post-stage barrier: O buffers now visible to all waves

  // ---- proj: wave w computes cols [w*32, w*32+32); K-step ks reads wave-ks's O ----
  {
    f4 po[4][2];
#pragma unroll
    for (int mi = 0; mi < 4; ++mi) {
      po[mi][0] = fz;
      po[mi][1] = fz;
    }
    bf16x8 a[4];
#pragma unroll
    for (int mi = 0; mi < 4; ++mi) {
      const int row = mi * 16 + lr;
      a[mi] = *(const bf16x8*)(lds + 49152 + row * 72 + lhi * 16);
    }
#pragma unroll
    for (int ks = 0; ks < 12; ++ks) {
      const int kn = ks < 11 ? ks + 1 : 0;
      bf16x8 an[4];
#pragma unroll
      for (int mi = 0; mi < 4; ++mi) {
        const int row = mi * 16 + lr;
        an[mi] = *(const bf16x8*)(lds + 49152 + kn * 9216 + row * 72 + lhi * 16);
      }
      const bf16x8 nw0 = fw[kn * 64], nw1 = fw[(12 + kn) * 64];
      __builtin_amdgcn_s_setprio(1);
#pragma unroll
      for (int mi = 0; mi < 4; ++mi) {
        po[mi][0] = MFMA(a[mi], cw0, po[mi][0]);
        po[mi][1] = MFMA(a[mi], cw1, po[mi][1]);
      }
      __builtin_amdgcn_s_setprio(0);
#pragma unroll
      for (int mi = 0; mi < 4; ++mi) a[mi] = an[mi];
      cw0 = nw0;
      cw1 = nw1;
    }
    float* ob = out + (size_t)b * 24576;
    const float pb0 = proj_b[w * 32 + lr];
    const float pb1 = proj_b[w * 32 + 16 + lr];
#pragma unroll
    for (int mi = 0; mi < 4; ++mi) {
#pragma unroll
      for (int r = 0; r < 4; ++r) {
        const int row = mi * 16 + lhi * 4 + r;
        ob[row * 384 + w * 32 + lr] = po[mi][0][r] + pb0;
        ob[row * 384 + w * 32 + 16 + lr] = po[mi][1][r] + pb1;
      }
    }
  }
}

extern "C" void kernel_launch(void* const* d_in, const int* in_sizes, int n_in,
                              void* d_out, int out_size, void* d_ws, size_t ws_size,
                              hipStream_t stream) {
  const float* x = (const float*)d_in[0];
  const float* mask = (const float*)d_in[1];
  const float* qkv_w = (const float*)d_in[2];
  const float* q_bias = (const float*)d_in[3];
  const float* v_bias = (const float*)d_in[4];
  const float* rpe_w1 = (const float*)d_in[5];
  const float* rpe_b1 = (const float*)d_in[6];
  const float* rpe_w2 = (const float*)d_in[7];
  const float* proj_w = (const float*)d_in[8];
  const float* proj_b = (const float*)d_in[9];
  const float* coords = (const float*)d_in[10];
  const int* rel = (const int*)d_in[11];
  float* out = (float*)d_out;

  char* ws = (char*)d_ws;
  float* bias_t = (float*)(ws);                              // 196608 B
  __bf16* qkvp = (__bf16*)(ws + 196608);                     // 884736 B
  __bf16* projp = (__bf16*)(ws + 1081344);                   // 294912 B
  float* table = (float*)(ws + 1376256);                     // 10800 B
  unsigned long long* maskb = (unsigned long long*)(ws + 1387056);  // 18432 B

  k_prep<<<354, 256, 0, stream>>>(qkv_w, proj_w, mask, coords, rpe_w1, rpe_b1,
                                  rpe_w2, qkvp, projp, maskb, table);
  k_bias_gather<<<192, 256, 0, stream>>>(table, rel, bias_t);
  k_fused<<<2304, 768, 0, stream>>>(x, maskb, q_bias, v_bias, bias_t,
                                    (const bf16x8*)qkvp, (const bf16x8*)projp,
                                    proj_b, out);
}

// Round 17
// 312.361 us; speedup vs baseline: 1.0064x; 1.0064x over previous
//
#include <hip/hip_runtime.h>

typedef __attribute__((ext_vector_type(8))) __bf16 bf16x8;
typedef __attribute__((ext_vector_type(4))) float f4;
typedef __attribute__((ext_vector_type(2))) unsigned int u32x2;

#define MFMA(a, b, c) __builtin_amdgcn_mfma_f32_16x16x32_bf16((a), (b), (c), 0, 0, 0)

// geometry: N=64 tokens, C=384, H=12 heads, HD=32, NW=36 masks, B=2304 windows
// ws layout (bytes):
//   [0, 196608)         bias_t  f32 [12][64][64]
//   [196608, 1081344)   qkvp    bf16 B-fragments: frag=(nb*12+ks), nb in [0,72)
//   [1081344, 1376256)  projp   bf16 B-fragments: nb in [0,24)
//   [1376256, 1387056)  table   f32 [225][12]
//   [1387056, 1405488)  maskb   u64 [36][64] packed mask bits (1 = masked)

__device__ inline unsigned pk2(float a, float b) {
  unsigned short ha = __builtin_bit_cast(unsigned short, (__bf16)a);
  unsigned short hb = __builtin_bit_cast(unsigned short, (__bf16)b);
  return (unsigned)ha | ((unsigned)hb << 16);
}

// Fused prep: blocks [0,288) pack_w, [288,297) maskbits, [297,354) rpe_table (4 pts/block)
__global__ void k_prep(const float* __restrict__ qkv_w,
                       const float* __restrict__ proj_w,
                       const float* __restrict__ mask,
                       const float* __restrict__ coords,
                       const float* __restrict__ w1,
                       const float* __restrict__ b1,
                       const float* __restrict__ w2,
                       __bf16* __restrict__ qkvp, __bf16* __restrict__ projp,
                       unsigned long long* __restrict__ maskb,
                       float* __restrict__ table) {
  const int blk = blockIdx.x;
  if (blk < 288) {
    const int gid = blk * 256 + threadIdx.x;  // 73728 total
    const int frag = gid >> 6, lane = gid & 63;
    const int lr = lane & 15, lhi = lane >> 4;
    const float* src;
    __bf16* dst;
    if (frag < 864) {
      const int nb = frag / 12, ks = frag % 12;
      src = qkv_w + (nb * 16 + lr) * 384 + ks * 32 + lhi * 8;
      dst = qkvp + (size_t)frag * 512 + lane * 8;
    } else {
      const int f2 = frag - 864;
      const int nb = f2 / 12, ks = f2 % 12;
      src = proj_w + (nb * 16 + lr) * 384 + ks * 32 + lhi * 8;
      dst = projp + (size_t)f2 * 512 + lane * 8;
    }
#pragma unroll
    for (int j = 0; j < 8; ++j) dst[j] = (__bf16)src[j];
  } else if (blk < 297) {
    const int i = (blk - 288) * 256 + threadIdx.x;  // 2304 total
    const float* mrow = mask + (size_t)i * 64;
    unsigned long long bits = 0ull;
#pragma unroll
    for (int k = 0; k < 64; ++k)
      bits |= (unsigned long long)(mrow[k] < -50.f ? 1u : 0u) << k;
    maskb[i] = bits;
  } else {
    const int p = (blk - 297) * 4 + (threadIdx.x >> 6);  // 0..227, guard 225
    const int lane = threadIdx.x & 63;
    if (p >= 225) return;
    const float c0 = coords[p * 2 + 0], c1 = coords[p * 2 + 1];
    float hm[8];
#pragma unroll
    for (int t = 0; t < 8; ++t) {
      const int j = lane * 8 + t;
      float v = fmaf(c0, w1[j * 2 + 0], fmaf(c1, w1[j * 2 + 1], b1[j]));
      hm[t] = v > 0.f ? v : 0.f;
    }
    for (int h = 0; h < 12; ++h) {
      float s = 0.f;
#pragma unroll
      for (int t = 0; t < 8; ++t) s = fmaf(hm[t], w2[h * 512 + lane * 8 + t], s);
      for (int off = 32; off >= 1; off >>= 1) s += __shfl_xor(s, off);
      if (lane == 0) table[p * 12 + h] = s;
    }
  }
}

__global__ void k_bias_gather(const float* __restrict__ table,
                              const int* __restrict__ rel,
                              float* __restrict__ bias_t) {
  const int idx = blockIdx.x * 256 + threadIdx.x;  // 49152 total
  const int h = idx >> 12;
  const int r = idx & 4095;
  bias_t[idx] = table[rel[r] * 12 + h];
}

// Fused kernel: one window per block; 768 threads = 12 waves, ONE head per wave.
// LDS: [0,49152)  X bf16 64 rows * 768B, byte ^= ((row&7)<<4)
//      [49152 + w*9216): wave-private q (64*72B) / k (+4608, 64*72B);
//         P overlays both (64*144B); O then overlays q (64*72B) and is read
//         CROSS-WAVE by the proj phase (wave w reads buffer ks for K-step ks).
// Phases: stage X | MERGED qkv proj (one A-read -> 6 MFMAs, 96 accs, reg-budgeted)
//         | S^T=mfma(K,Q) | no-max softmax (bitmask) | PV (V via lane shuffle)
//         | O->own buffer | ONE barrier | proj GEMM (cross-wave A)
__global__ __launch_bounds__(768, 3) void k_fused(
    const float* __restrict__ x, const unsigned long long* __restrict__ maskb,
    const float* __restrict__ q_bias, const float* __restrict__ v_bias,
    const float* __restrict__ bias_t, const bf16x8* __restrict__ qkvp,
    const bf16x8* __restrict__ projp, const float* __restrict__ proj_b,
    float* __restrict__ out) {
  __shared__ __align__(16) char lds[159744];
  const int tid = threadIdx.x;
  const int b = blockIdx.x;
  const int w = tid >> 6, lane = tid & 63;
  const int lr = lane & 15, lhi = lane >> 4;
  const int h = w;  // one head per wave
  char* wb = lds + 49152 + w * 9216;
  const int mb = b % 36;
  const float scale = 0.17677669529663687f;  // 32^-0.5
  const f4 fz = {0.f, 0.f, 0.f, 0.f};

  // hoist first qkv weight loads: latency hides under X staging
  const bf16x8* fq = qkvp + h * 1536 + lane;
  const bf16x8* fk = qkvp + 18432 + h * 1536 + lane;
  const bf16x8* fv = qkvp + 36864 + h * 1536 + lane;
  bf16x8 cq0 = fq[0], cq1 = fq[768];
  bf16x8 ck0 = fk[0], ck1 = fk[768];
  bf16x8 cv0 = fv[0], cv1 = fv[768];

  // ---- stage X (64x384 fp32 -> bf16) into swizzled LDS ----
  {
    const f4* xp = (const f4*)(x + (size_t)b * 24576);
#pragma unroll
    for (int it = 0; it < 8; ++it) {
      const int idx = tid + it * 768;  // 0..6143 float4's
      const int row = idx / 96;
      const int c4 = idx % 96;
      f4 v = xp[idx];
      unsigned long long pkw =
          (unsigned long long)pk2(v[0], v[1]) |
          ((unsigned long long)pk2(v[2], v[3]) << 32);
      *(unsigned long long*)(lds + row * 768 + ((c4 * 8) ^ ((row & 7) << 4))) = pkw;
    }
  }
  __syncthreads();

  // ---- MERGED q,k,v projection (64x32 each, K=384): mi-inner, 1 A-read -> 6 MFMAs ----
  unsigned pkv[4][2][2];
  {
    f4 aq[4][2], ak[4][2], av[4][2];
#pragma unroll
    for (int mi = 0; mi < 4; ++mi)
#pragma unroll
      for (int nj = 0; nj < 2; ++nj) {
        aq[mi][nj] = fz;
        ak[mi][nj] = fz;
        av[mi][nj] = fz;
      }
#pragma unroll
    for (int ks = 0; ks < 12; ++ks) {
#pragma unroll
      for (int mi = 0; mi < 4; ++mi) {
        const int row = mi * 16 + lr;
        const bf16x8 a = *(const bf16x8*)(lds + row * 768 +
                                          ((ks * 64 + lhi * 16) ^ ((row & 7) << 4)));
        __builtin_amdgcn_s_setprio(1);
        aq[mi][0] = MFMA(a, cq0, aq[mi][0]);
        aq[mi][1] = MFMA(a, cq1, aq[mi][1]);
        ak[mi][0] = MFMA(a, ck0, ak[mi][0]);
        ak[mi][1] = MFMA(a, ck1, ak[mi][1]);
        av[mi][0] = MFMA(a, cv0, av[mi][0]);
        av[mi][1] = MFMA(a, cv1, av[mi][1]);
        __builtin_amdgcn_s_setprio(0);
      }
      // prefetch-lite: next-ks weights into the same SSA vars (no dual reg set)
      const int kn = ks < 11 ? ks + 1 : 0;  // clamped: values unused at ks=11
      cq0 = fq[kn * 64];
      cq1 = fq[(12 + kn) * 64];
      ck0 = fk[kn * 64];
      ck1 = fk[(12 + kn) * 64];
      cv0 = fv[kn * 64];
      cv1 = fv[(12 + kn) * 64];
    }
    // scatter q (bias+scale), k into wave-private LDS; pack v into registers
    const float qb0 = q_bias[h * 32 + lr], qb1 = q_bias[h * 32 + 16 + lr];
    const float vb0 = v_bias[h * 32 + lr], vb1 = v_bias[h * 32 + 16 + lr];
#pragma unroll
    for (int mi = 0; mi < 4; ++mi) {
#pragma unroll
      for (int r = 0; r < 4; ++r) {
        const int row = mi * 16 + lhi * 4 + r;  // token
        *(__bf16*)(wb + row * 72 + lr * 2) = (__bf16)((aq[mi][0][r] + qb0) * scale);
        *(__bf16*)(wb + row * 72 + (16 + lr) * 2) = (__bf16)((aq[mi][1][r] + qb1) * scale);
        *(__bf16*)(wb + 4608 + row * 72 + lr * 2) = (__bf16)ak[mi][0][r];
        *(__bf16*)(wb + 4608 + row * 72 + (16 + lr) * 2) = (__bf16)ak[mi][1][r];
      }
      pkv[mi][0][0] = pk2(av[mi][0][0] + vb0, av[mi][0][1] + vb0);
      pkv[mi][0][1] = pk2(av[mi][0][2] + vb0, av[mi][0][3] + vb0);
      pkv[mi][1][0] = pk2(av[mi][1][0] + vb1, av[mi][1][1] + vb1);
      pkv[mi][1][1] = pk2(av[mi][1][2] + vb1, av[mi][1][3] + vb1);
    }
  }

  // ---- S^T = mfma(K, Q): st[mi][nj] holds S[q = nj*16+lr][k = mi*16+lhi*4+r] ----
  f4 st[4][4];
  {
    bf16x8 fqv[4], fkv[4];
#pragma unroll
    for (int i = 0; i < 4; ++i) {
      const int rt = i * 16 + lr;
      fqv[i] = *(const bf16x8*)(wb + rt * 72 + lhi * 16);          // Q frag
      fkv[i] = *(const bf16x8*)(wb + 4608 + rt * 72 + lhi * 16);   // K frag
    }
    __builtin_amdgcn_s_setprio(1);
#pragma unroll
    for (int mi = 0; mi < 4; ++mi)
#pragma unroll
      for (int nj = 0; nj < 4; ++nj) st[mi][nj] = MFMA(fkv[mi], fqv[nj], fz);
    __builtin_amdgcn_s_setprio(0);
  }

  // ---- no-max softmax over k (bitmask zeroing); P -> 144-stride LDS [q][k] ----
  {
    const float* bp = bias_t + h * 4096;
    const unsigned long long* mbp = maskb + mb * 64;
#pragma unroll
    for (int nj = 0; nj < 4; ++nj) {
      const int q = nj * 16 + lr;
      const unsigned long long mbits = mbp[q];
      float lsum = 0.f;
#pragma unroll
      for (int mi = 0; mi < 4; ++mi) {
        const int kbase = mi * 16 + lhi * 4;
        const f4 bb = *(const f4*)(bp + q * 64 + kbase);
        const unsigned b4 = (unsigned)(mbits >> kbase) & 0xFu;
        f4 e;
#pragma unroll
        for (int r = 0; r < 4; ++r)
          e[r] = ((b4 >> r) & 1u) ? 0.f : __expf(st[mi][nj][r] + bb[r]);
        st[mi][nj] = e;
        lsum += (e[0] + e[1]) + (e[2] + e[3]);
      }
      lsum += __shfl_xor(lsum, 16);
      lsum += __shfl_xor(lsum, 32);
      const float inv = 1.0f / lsum;
#pragma unroll
      for (int mi = 0; mi < 4; ++mi) {
        u32x2 pw;
        pw[0] = pk2(st[mi][nj][0] * inv, st[mi][nj][1] * inv);
        pw[1] = pk2(st[mi][nj][2] * inv, st[mi][nj][3] * inv);
        *(u32x2*)(wb + q * 144 + mi * 32 + lhi * 8) = pw;
      }
    }
  }

  // ---- O = P V : P from 144-stride LDS (conflict-free b128), V via lane shuffle ----
  f4 o[4][2];
#pragma unroll
  for (int mi = 0; mi < 4; ++mi) {
    o[mi][0] = fz;
    o[mi][1] = fz;
  }
  {
    const int srcA = lr + 32 * (lhi & 1);
    const int srcB = srcA + 16;
    const bool hiSel = lhi >= 2;
#pragma unroll
    for (int kh = 0; kh < 2; ++kh) {
      bf16x8 pa[4];
#pragma unroll
      for (int mi = 0; mi < 4; ++mi) {
        const int row = mi * 16 + lr;
        pa[mi] = *(const bf16x8*)(wb + row * 144 + kh * 64 + lhi * 16);
      }
      bf16x8 vv[2];
#pragma unroll
      for (int nj = 0; nj < 2; ++nj) {
        const unsigned a0 = (unsigned)__shfl((int)pkv[2 * kh][nj][0], srcA);
        const unsigned b0 = (unsigned)__shfl((int)pkv[2 * kh + 1][nj][0], srcA);
        const unsigned a1 = (unsigned)__shfl((int)pkv[2 * kh][nj][1], srcA);
        const unsigned b1 = (unsigned)__shfl((int)pkv[2 * kh + 1][nj][1], srcA);
        const unsigned a2 = (unsigned)__shfl((int)pkv[2 * kh][nj][0], srcB);
        const unsigned b2 = (unsigned)__shfl((int)pkv[2 * kh + 1][nj][0], srcB);
        const unsigned a3 = (unsigned)__shfl((int)pkv[2 * kh][nj][1], srcB);
        const unsigned b3 = (unsigned)__shfl((int)pkv[2 * kh + 1][nj][1], srcB);
        union {
          unsigned u[4];
          bf16x8 v8;
        } cv;
        cv.u[0] = hiSel ? b0 : a0;
        cv.u[1] = hiSel ? b1 : a1;
        cv.u[2] = hiSel ? b2 : a2;
        cv.u[3] = hiSel ? b3 : a3;
        vv[nj] = cv.v8;
      }
      __builtin_amdgcn_s_setprio(1);
#pragma unroll
      for (int mi = 0; mi < 4; ++mi) {
        o[mi][0] = MFMA(pa[mi], vv[0], o[mi][0]);
        o[mi][1] = MFMA(pa[mi], vv[1], o[mi][1]);
      }
      __builtin_amdgcn_s_setprio(0);
    }
  }

  // ---- hoist proj weight first-loads: L2 latency hides under scatter + barrier ----
  const bf16x8* fw = projp + w * 1536 + lane;
  bf16x8 cw0 = fw[0], cw1 = fw[768];

  // ---- O -> own buffer (72-stride, conflict-free; overlays dead q/P region) ----
#pragma unroll
  for (int mi = 0; mi < 4; ++mi) {
#pragma unroll
    for (int r = 0; r < 4; ++r) {
      const int row = mi * 16 + lhi * 4 + r;
      *(__bf16*)(wb + row * 72 + lr * 2) = (__bf16)o[mi][0][r];
      *(__bf16*)(wb + row * 72 + (16 + lr) * 2) = (__bf16)o[mi][1][r];
    }
  }
  __syncthreads();  // the ONLY post-stage barrier: O buffers now visible to all waves

  // ---- proj: wave w computes cols [w*32, w*32+32); K-step ks reads wave-ks's O ----
  {
    f4 po[4][2];
#pragma unroll
    for (int mi = 0; mi < 4; ++mi) {
      po[mi][0] = fz;
      po[mi][1] = fz;
    }
    bf16x8 a[4];
#pragma unroll
    for (int mi = 0; mi < 4; ++mi) {
      const int row = mi * 16 + lr;
      a[mi] = *(const bf16x8*)(lds + 49152 + row * 72 + lhi * 16);
    }
#pragma unroll
    for (int ks = 0; ks < 12; ++ks) {
      const int kn = ks < 11 ? ks + 1 : 0;
      bf16x8 an[4];
#pragma unroll
      for (int mi = 0; mi < 4; ++mi) {
        const int row = mi * 16 + lr;
        an[mi] = *(const bf16x8*)(lds + 49152 + kn * 9216 + row * 72 + lhi * 16);
      }
      const bf16x8 nw0 = fw[kn * 64], nw1 = fw[(12 + kn) * 64];
      __builtin_amdgcn_s_setprio(1);
#pragma unroll
      for (int mi = 0; mi < 4; ++mi) {
        po[mi][0] = MFMA(a[mi], cw0, po[mi][0]);
        po[mi][1] = MFMA(a[mi], cw1, po[mi][1]);
      }
      __builtin_amdgcn_s_setprio(0);
#pragma unroll
      for (int mi = 0; mi < 4; ++mi) a[mi] = an[mi];
      cw0 = nw0;
      cw1 = nw1;
    }
    float* ob = out + (size_t)b * 24576;
    const float pb0 = proj_b[w * 32 + lr];
    const float pb1 = proj_b[w * 32 + 16 + lr];
#pragma unroll
    for (int mi = 0; mi < 4; ++mi) {
#pragma unroll
      for (int r = 0; r < 4; ++r) {
        const int row = mi * 16 + lhi * 4 + r;
        ob[row * 384 + w * 32 + lr] = po[mi][0][r] + pb0;
        ob[row * 384 + w * 32 + 16 + lr] = po[mi][1][r] + pb1;
      }
    }
  }
}

extern "C" void kernel_launch(void* const* d_in, const int* in_sizes, int n_in,
                              void* d_out, int out_size, void* d_ws, size_t ws_size,
                              hipStream_t stream) {
  const float* x = (const float*)d_in[0];
  const float* mask = (const float*)d_in[1];
  const float* qkv_w = (const float*)d_in[2];
  const float* q_bias = (const float*)d_in[3];
  const float* v_bias = (const float*)d_in[4];
  const float* rpe_w1 = (const float*)d_in[5];
  const float* rpe_b1 = (const float*)d_in[6];
  const float* rpe_w2 = (const float*)d_in[7];
  const float* proj_w = (const float*)d_in[8];
  const float* proj_b = (const float*)d_in[9];
  const float* coords = (const float*)d_in[10];
  const int* rel = (const int*)d_in[11];
  float* out = (float*)d_out;

  char* ws = (char*)d_ws;
  float* bias_t = (float*)(ws);                              // 196608 B
  __bf16* qkvp = (__bf16*)(ws + 196608);                     // 884736 B
  __bf16* projp = (__bf16*)(ws + 1081344);                   // 294912 B
  float* table = (float*)(ws + 1376256);                     // 10800 B
  unsigned long long* maskb = (unsigned long long*)(ws + 1387056);  // 18432 B

  k_prep<<<354, 256, 0, stream>>>(qkv_w, proj_w, mask, coords, rpe_w1, rpe_b1,
                                  rpe_w2, qkvp, projp, maskb, table);
  k_bias_gather<<<192, 256, 0, stream>>>(table, rel, bias_t);
  k_fused<<<2304, 768, 0, stream>>>(x, maskb, q_bias, v_bias, bias_t,
                                    (const bf16x8*)qkvp, (const bf16x8*)projp,
                                    proj_b, out);
}